// Round 1
// baseline (1412.858 us; speedup 1.0000x reference)
//
#include <hip/hip_runtime.h>

static constexpr int IN_F = 256;
static constexpr int OUT_F = 128;

// ---------------------------------------------------------------------------
// GEMM: H[M,128] = X[M,256] * W[256,128] + bias
// fp32 vector-ALU (no fp32 MFMA on CDNA4). Tile BM=64, BN=128, BK=16.
// 256 threads (16x16), micro-tile 4 rows x 8 cols per thread.
// ---------------------------------------------------------------------------
__global__ __launch_bounds__(256) void gemm_bias_kernel(
    const float* __restrict__ X, const float* __restrict__ W,
    const float* __restrict__ bias, float* __restrict__ H, int M) {
  __shared__ float As[16][64];    // A tile stored transposed: As[k][m]
  __shared__ float Bs[16][128];   // B tile: Bs[k][n]

  const int tid = threadIdx.x;
  const int tx = tid & 15;        // 0..15 -> 8 output cols each
  const int ty = tid >> 4;        // 0..15 -> 4 output rows each
  const int row0 = blockIdx.x * 64;

  float acc[4][8];
#pragma unroll
  for (int i = 0; i < 4; ++i)
#pragma unroll
    for (int j = 0; j < 8; ++j) acc[i][j] = 0.f;

  // A-tile load mapping: 64 rows x 16 cols = 256 float4; 1 per thread.
  const int arow = tid >> 2;             // 0..63
  const int acol = (tid & 3) << 2;       // 0,4,8,12
  const int grow_a = row0 + arow;
  // B-tile load mapping: 16 x 128 = 512 float4; 2 per thread.
  const int bk = tid >> 5;               // 0..7
  const int bn = (tid & 31) << 2;        // 0..124

  for (int k0 = 0; k0 < IN_F; k0 += 16) {
    float4 av;
    if (grow_a < M)
      av = *reinterpret_cast<const float4*>(X + (size_t)grow_a * IN_F + k0 + acol);
    else
      av = make_float4(0.f, 0.f, 0.f, 0.f);
    As[acol + 0][arow] = av.x;
    As[acol + 1][arow] = av.y;
    As[acol + 2][arow] = av.z;
    As[acol + 3][arow] = av.w;
    *reinterpret_cast<float4*>(&Bs[bk][bn]) =
        *reinterpret_cast<const float4*>(W + (size_t)(k0 + bk) * OUT_F + bn);
    *reinterpret_cast<float4*>(&Bs[bk + 8][bn]) =
        *reinterpret_cast<const float4*>(W + (size_t)(k0 + bk + 8) * OUT_F + bn);
    __syncthreads();

#pragma unroll
    for (int kk = 0; kk < 16; ++kk) {
      float a[4], b[8];
#pragma unroll
      for (int i = 0; i < 4; ++i) a[i] = As[kk][ty * 4 + i];
#pragma unroll
      for (int j = 0; j < 8; ++j) b[j] = Bs[kk][tx * 8 + j];
#pragma unroll
      for (int i = 0; i < 4; ++i)
#pragma unroll
        for (int j = 0; j < 8; ++j) acc[i][j] = fmaf(a[i], b[j], acc[i][j]);
    }
    __syncthreads();
  }

  float bv[8];
#pragma unroll
  for (int j = 0; j < 8; ++j) bv[j] = bias[tx * 8 + j];

#pragma unroll
  for (int i = 0; i < 4; ++i) {
    const int grow = row0 + ty * 4 + i;
    if (grow < M) {
      float4 o0, o1;
      o0.x = acc[i][0] + bv[0];
      o0.y = acc[i][1] + bv[1];
      o0.z = acc[i][2] + bv[2];
      o0.w = acc[i][3] + bv[3];
      o1.x = acc[i][4] + bv[4];
      o1.y = acc[i][5] + bv[5];
      o1.z = acc[i][6] + bv[6];
      o1.w = acc[i][7] + bv[7];
      float4* dstp = reinterpret_cast<float4*>(H + (size_t)grow * OUT_F + tx * 8);
      dstp[0] = o0;
      dstp[1] = o1;
    }
  }
}

// ---------------------------------------------------------------------------
// SpMM scatter: out[dst[e]] += vals[e] * H[src[e]]
// One 32-lane group per edge; each lane owns 4 consecutive floats (float4
// load from H, 4 fp32 atomicAdds into out). 8 edges per 256-thread block
// per sweep, grid-stride over E.
// ---------------------------------------------------------------------------
__global__ __launch_bounds__(256) void spmm_atomic_kernel(
    const float* __restrict__ H, const float* __restrict__ vals,
    const int* __restrict__ src, const int* __restrict__ dst,
    float* __restrict__ out, int E) {
  const int lane = threadIdx.x & 31;
  const int grp = threadIdx.x >> 5;  // 0..7
  const int stride = gridDim.x * 8;
  for (int e = blockIdx.x * 8 + grp; e < E; e += stride) {
    const int s = src[e];
    const int d = dst[e];
    const float v = vals[e];
    const float4 hv =
        reinterpret_cast<const float4*>(H + (size_t)s * OUT_F)[lane];
    float* o = out + (size_t)d * OUT_F + lane * 4;
    atomicAdd(o + 0, v * hv.x);
    atomicAdd(o + 1, v * hv.y);
    atomicAdd(o + 2, v * hv.z);
    atomicAdd(o + 3, v * hv.w);
  }
}

// ---------------------------------------------------------------------------
extern "C" void kernel_launch(void* const* d_in, const int* in_sizes, int n_in,
                              void* d_out, int out_size, void* d_ws,
                              size_t ws_size, hipStream_t stream) {
  const float* X = (const float*)d_in[0];        // [M, 256]
  const float* W = (const float*)d_in[1];        // [256, 128]
  const float* bias = (const float*)d_in[2];     // [128]
  const float* adj_vals = (const float*)d_in[3]; // [E]
  const int* edge_src = (const int*)d_in[4];     // [E]
  const int* edge_dst = (const int*)d_in[5];     // [E]
  float* out = (float*)d_out;                    // [M, 128]
  float* H = (float*)d_ws;                       // [M, 128] scratch

  const int M = in_sizes[0] / IN_F;  // 50000
  const int E = in_sizes[3];         // 800000

  // out must be zeroed every call (atomics accumulate; harness poisons once).
  hipMemsetAsync(d_out, 0, (size_t)out_size * sizeof(float), stream);

  dim3 gemm_grid((M + 63) / 64);
  gemm_bias_kernel<<<gemm_grid, 256, 0, stream>>>(X, W, bias, H, M);

  spmm_atomic_kernel<<<2048, 256, 0, stream>>>(H, adj_vals, edge_src, edge_dst,
                                               out, E);
}

// Round 5
// 341.245 us; speedup vs baseline: 4.1403x; 4.1403x over previous
//
#include <hip/hip_runtime.h>

static constexpr int IN_F = 256;
static constexpr int OUT_F = 128;

// ---------------------------------------------------------------------------
// GEMM: H[M,128] = X[M,256] * W[256,128] + bias  (fp32 vector ALU)
// ---------------------------------------------------------------------------
__global__ __launch_bounds__(256) void gemm_bias_kernel(
    const float* __restrict__ X, const float* __restrict__ W,
    const float* __restrict__ bias, float* __restrict__ H, int M) {
  __shared__ float As[16][64];    // A tile transposed: As[k][m]
  __shared__ float Bs[16][128];   // B tile: Bs[k][n]

  const int tid = threadIdx.x;
  const int tx = tid & 15;
  const int ty = tid >> 4;
  const int row0 = blockIdx.x * 64;

  float acc[4][8];
#pragma unroll
  for (int i = 0; i < 4; ++i)
#pragma unroll
    for (int j = 0; j < 8; ++j) acc[i][j] = 0.f;

  const int arow = tid >> 2;
  const int acol = (tid & 3) << 2;
  const int grow_a = row0 + arow;
  const int bk = tid >> 5;
  const int bn = (tid & 31) << 2;

  for (int k0 = 0; k0 < IN_F; k0 += 16) {
    float4 av;
    if (grow_a < M)
      av = *reinterpret_cast<const float4*>(X + (size_t)grow_a * IN_F + k0 + acol);
    else
      av = make_float4(0.f, 0.f, 0.f, 0.f);
    As[acol + 0][arow] = av.x;
    As[acol + 1][arow] = av.y;
    As[acol + 2][arow] = av.z;
    As[acol + 3][arow] = av.w;
    *reinterpret_cast<float4*>(&Bs[bk][bn]) =
        *reinterpret_cast<const float4*>(W + (size_t)(k0 + bk) * OUT_F + bn);
    *reinterpret_cast<float4*>(&Bs[bk + 8][bn]) =
        *reinterpret_cast<const float4*>(W + (size_t)(k0 + bk + 8) * OUT_F + bn);
    __syncthreads();

#pragma unroll
    for (int kk = 0; kk < 16; ++kk) {
      float a[4], b[8];
#pragma unroll
      for (int i = 0; i < 4; ++i) a[i] = As[kk][ty * 4 + i];
#pragma unroll
      for (int j = 0; j < 8; ++j) b[j] = Bs[kk][tx * 8 + j];
#pragma unroll
      for (int i = 0; i < 4; ++i)
#pragma unroll
        for (int j = 0; j < 8; ++j) acc[i][j] = fmaf(a[i], b[j], acc[i][j]);
    }
    __syncthreads();
  }

  float bv[8];
#pragma unroll
  for (int j = 0; j < 8; ++j) bv[j] = bias[tx * 8 + j];

#pragma unroll
  for (int i = 0; i < 4; ++i) {
    const int grow = row0 + ty * 4 + i;
    if (grow < M) {
      float4 o0, o1;
      o0.x = acc[i][0] + bv[0]; o0.y = acc[i][1] + bv[1];
      o0.z = acc[i][2] + bv[2]; o0.w = acc[i][3] + bv[3];
      o1.x = acc[i][4] + bv[4]; o1.y = acc[i][5] + bv[5];
      o1.z = acc[i][6] + bv[6]; o1.w = acc[i][7] + bv[7];
      float4* dstp = reinterpret_cast<float4*>(H + (size_t)grow * OUT_F + tx * 8);
      dstp[0] = o0;
      dstp[1] = o1;
    }
  }
}

// ---------------------------------------------------------------------------
// CSR build: histogram -> single-block scan -> scatter edge ids
// ---------------------------------------------------------------------------
__global__ __launch_bounds__(256) void hist_kernel(const int* __restrict__ dst,
                                                   int* __restrict__ deg, int E) {
  int e = blockIdx.x * blockDim.x + threadIdx.x;
  if (e < E) atomicAdd(&deg[dst[e]], 1);
}

__global__ __launch_bounds__(1024) void scan_kernel(const int* __restrict__ deg,
                                                    int* __restrict__ off, int n) {
  __shared__ int partial[1024];
  const int tid = threadIdx.x;
  const int chunk = (n + 1023) / 1024;
  const int begin = tid * chunk;
  const int end = min(begin + chunk, n);
  int sum = 0;
  for (int i = begin; i < end; ++i) sum += deg[i];
  partial[tid] = sum;
  __syncthreads();
  // Hillis-Steele inclusive scan
  for (int d = 1; d < 1024; d <<= 1) {
    int v = (tid >= d) ? partial[tid - d] : 0;
    __syncthreads();
    partial[tid] += v;
    __syncthreads();
  }
  int prefix = (tid == 0) ? 0 : partial[tid - 1];
  for (int i = begin; i < end; ++i) {
    off[i] = prefix;
    prefix += deg[i];
  }
  if (tid == 1023) off[n] = prefix;
}

__global__ __launch_bounds__(256) void scatter_kernel(
    const int* __restrict__ dst, const int* __restrict__ off,
    int* __restrict__ cursor, int* __restrict__ perm, int E) {
  int e = blockIdx.x * blockDim.x + threadIdx.x;
  if (e < E) {
    int d = dst[e];
    int pos = off[d] + atomicAdd(&cursor[d], 1);
    perm[pos] = e;
  }
}

// ---------------------------------------------------------------------------
// Gather: one 64-lane wave per output node; lane owns 2 floats (float2).
// out[i] = sum_{e in in-edges(i)} vals[e] * H[src[e]]   — no fp32 atomics.
// ---------------------------------------------------------------------------
__global__ __launch_bounds__(256) void gather_kernel(
    const float* __restrict__ H, const float* __restrict__ vals,
    const int* __restrict__ src, const int* __restrict__ off,
    const int* __restrict__ perm, float* __restrict__ out, int M) {
  const int wave = (int)((blockIdx.x * blockDim.x + threadIdx.x) >> 6);
  const int lane = threadIdx.x & 63;
  if (wave >= M) return;
  const int b = off[wave];
  const int e = off[wave + 1];
  float accx = 0.f, accy = 0.f;
  for (int i = b; i < e; ++i) {
    const int id = perm[i];
    const float v = vals[id];
    const int s = src[id];
    const float2 hv = reinterpret_cast<const float2*>(H + (size_t)s * OUT_F)[lane];
    accx = fmaf(v, hv.x, accx);
    accy = fmaf(v, hv.y, accy);
  }
  float2 o; o.x = accx; o.y = accy;
  reinterpret_cast<float2*>(out + (size_t)wave * OUT_F)[lane] = o;
}

// ---------------------------------------------------------------------------
extern "C" void kernel_launch(void* const* d_in, const int* in_sizes, int n_in,
                              void* d_out, int out_size, void* d_ws,
                              size_t ws_size, hipStream_t stream) {
  const float* X = (const float*)d_in[0];        // [M, 256]
  const float* W = (const float*)d_in[1];        // [256, 128]
  const float* bias = (const float*)d_in[2];     // [128]
  const float* adj_vals = (const float*)d_in[3]; // [E]
  const int* edge_src = (const int*)d_in[4];     // [E]
  const int* edge_dst = (const int*)d_in[5];     // [E]
  float* out = (float*)d_out;                    // [M, 128]

  const int M = in_sizes[0] / IN_F;  // 50000
  const int E = in_sizes[3];         // 800000

  // Workspace layout (16B-aligned slices)
  char* ws = (char*)d_ws;
  size_t o = 0;
  auto take = [&](size_t bytes) {
    void* p = ws + o;
    o = (o + bytes + 15) & ~(size_t)15;
    return p;
  };
  float* H = (float*)take((size_t)M * OUT_F * sizeof(float));  // 25.6 MB
  int* off = (int*)take((size_t)(M + 1) * sizeof(int));
  int* deg = (int*)take((size_t)M * sizeof(int));
  int* cursor = (int*)take((size_t)M * sizeof(int));
  int* perm = (int*)take((size_t)E * sizeof(int));
  (void)ws_size;

  // Zero the two counter arrays (contiguous: deg then cursor)
  hipMemsetAsync(deg, 0, (size_t)2 * M * sizeof(int) + 16, stream);

  dim3 gemm_grid((M + 63) / 64);
  gemm_bias_kernel<<<gemm_grid, 256, 0, stream>>>(X, W, bias, H, M);

  hist_kernel<<<(E + 255) / 256, 256, 0, stream>>>(edge_dst, deg, E);
  scan_kernel<<<1, 1024, 0, stream>>>(deg, off, M);
  scatter_kernel<<<(E + 255) / 256, 256, 0, stream>>>(edge_dst, off, cursor,
                                                      perm, E);

  const int waves_per_block = 4;  // 256 threads
  dim3 gather_grid((M + waves_per_block - 1) / waves_per_block);
  gather_kernel<<<gather_grid, 256, 0, stream>>>(H, adj_vals, edge_src, off,
                                                 perm, out, M);
}

// Round 6
// 294.053 us; speedup vs baseline: 4.8048x; 1.1605x over previous
//
#include <hip/hip_runtime.h>

static constexpr int IN_F = 256;
static constexpr int OUT_F = 128;

// ---------------------------------------------------------------------------
// GEMM: H[M,128] = X[M,256] * W[256,128] + bias  (fp32 vector ALU)
// ---------------------------------------------------------------------------
__global__ __launch_bounds__(256) void gemm_bias_kernel(
    const float* __restrict__ X, const float* __restrict__ W,
    const float* __restrict__ bias, float* __restrict__ H, int M) {
  __shared__ float As[16][64];    // A tile transposed: As[k][m]
  __shared__ float Bs[16][128];   // B tile: Bs[k][n]

  const int tid = threadIdx.x;
  const int tx = tid & 15;
  const int ty = tid >> 4;
  const int row0 = blockIdx.x * 64;

  float acc[4][8];
#pragma unroll
  for (int i = 0; i < 4; ++i)
#pragma unroll
    for (int j = 0; j < 8; ++j) acc[i][j] = 0.f;

  const int arow = tid >> 2;
  const int acol = (tid & 3) << 2;
  const int grow_a = row0 + arow;
  const int bk = tid >> 5;
  const int bn = (tid & 31) << 2;

  for (int k0 = 0; k0 < IN_F; k0 += 16) {
    float4 av;
    if (grow_a < M)
      av = *reinterpret_cast<const float4*>(X + (size_t)grow_a * IN_F + k0 + acol);
    else
      av = make_float4(0.f, 0.f, 0.f, 0.f);
    As[acol + 0][arow] = av.x;
    As[acol + 1][arow] = av.y;
    As[acol + 2][arow] = av.z;
    As[acol + 3][arow] = av.w;
    *reinterpret_cast<float4*>(&Bs[bk][bn]) =
        *reinterpret_cast<const float4*>(W + (size_t)(k0 + bk) * OUT_F + bn);
    *reinterpret_cast<float4*>(&Bs[bk + 8][bn]) =
        *reinterpret_cast<const float4*>(W + (size_t)(k0 + bk + 8) * OUT_F + bn);
    __syncthreads();

#pragma unroll
    for (int kk = 0; kk < 16; ++kk) {
      float a[4], b[8];
#pragma unroll
      for (int i = 0; i < 4; ++i) a[i] = As[kk][ty * 4 + i];
#pragma unroll
      for (int j = 0; j < 8; ++j) b[j] = Bs[kk][tx * 8 + j];
#pragma unroll
      for (int i = 0; i < 4; ++i)
#pragma unroll
        for (int j = 0; j < 8; ++j) acc[i][j] = fmaf(a[i], b[j], acc[i][j]);
    }
    __syncthreads();
  }

  float bv[8];
#pragma unroll
  for (int j = 0; j < 8; ++j) bv[j] = bias[tx * 8 + j];

#pragma unroll
  for (int i = 0; i < 4; ++i) {
    const int grow = row0 + ty * 4 + i;
    if (grow < M) {
      float4 o0, o1;
      o0.x = acc[i][0] + bv[0]; o0.y = acc[i][1] + bv[1];
      o0.z = acc[i][2] + bv[2]; o0.w = acc[i][3] + bv[3];
      o1.x = acc[i][4] + bv[4]; o1.y = acc[i][5] + bv[5];
      o1.z = acc[i][6] + bv[6]; o1.w = acc[i][7] + bv[7];
      float4* dstp = reinterpret_cast<float4*>(H + (size_t)grow * OUT_F + tx * 8);
      dstp[0] = o0;
      dstp[1] = o1;
    }
  }
}

// ---------------------------------------------------------------------------
// CSR build: histogram -> single-block scan -> scatter edge ids
// ---------------------------------------------------------------------------
__global__ __launch_bounds__(256) void hist_kernel(const int* __restrict__ dst,
                                                   int* __restrict__ deg, int E) {
  int e = blockIdx.x * blockDim.x + threadIdx.x;
  if (e < E) atomicAdd(&deg[dst[e]], 1);
}

__global__ __launch_bounds__(1024) void scan_kernel(const int* __restrict__ deg,
                                                    int* __restrict__ off, int n) {
  __shared__ int partial[1024];
  const int tid = threadIdx.x;
  const int chunk = (n + 1023) / 1024;
  const int begin = tid * chunk;
  const int end = min(begin + chunk, n);
  int sum = 0;
  for (int i = begin; i < end; ++i) sum += deg[i];
  partial[tid] = sum;
  __syncthreads();
  // Hillis-Steele inclusive scan
  for (int d = 1; d < 1024; d <<= 1) {
    int v = (tid >= d) ? partial[tid - d] : 0;
    __syncthreads();
    partial[tid] += v;
    __syncthreads();
  }
  int prefix = (tid == 0) ? 0 : partial[tid - 1];
  for (int i = begin; i < end; ++i) {
    off[i] = prefix;
    prefix += deg[i];
  }
  if (tid == 1023) off[n] = prefix;
}

__global__ __launch_bounds__(256) void scatter_kernel(
    const int* __restrict__ dst, const int* __restrict__ off,
    int* __restrict__ cursor, int* __restrict__ perm, int E) {
  int e = blockIdx.x * blockDim.x + threadIdx.x;
  if (e < E) {
    int d = dst[e];
    int pos = off[d] + atomicAdd(&cursor[d], 1);
    perm[pos] = e;
  }
}

// ---------------------------------------------------------------------------
// Gather v2: one 64-lane wave per output node.
// Lane-parallel metadata load (perm/src/vals for up to 64 edges at once),
// shfl-broadcast inside the wave, and 8 independent H-row loads in flight.
// No fp32 atomics; out written exactly once.
// ---------------------------------------------------------------------------
__device__ __forceinline__ float2 h_row2(const float* __restrict__ H, int s,
                                         int lane) {
  return reinterpret_cast<const float2*>(H + (size_t)s * OUT_F)[lane];
}

__global__ __launch_bounds__(256) void gather_kernel(
    const float* __restrict__ H, const float* __restrict__ vals,
    const int* __restrict__ src, const int* __restrict__ off,
    const int* __restrict__ perm, float* __restrict__ out, int M) {
  const int wave = (int)((blockIdx.x * blockDim.x + threadIdx.x) >> 6);
  const int lane = threadIdx.x & 63;
  if (wave >= M) return;
  const int b = off[wave];
  const int e = off[wave + 1];
  float accx = 0.f, accy = 0.f;

  for (int base = b; base < e; base += 64) {
    const int n = min(64, e - base);
    // Parallel metadata fetch: lane j holds edge (base+j)'s src and val.
    int s = 0;
    float v = 0.f;
    if (lane < n) {
      const int id = perm[base + lane];
      v = vals[id];
      s = src[id];
    }
    int k = 0;
    // 8 independent row loads in flight per step.
    for (; k + 8 <= n; k += 8) {
      const int s0 = __shfl(s, k + 0, 64);
      const int s1 = __shfl(s, k + 1, 64);
      const int s2 = __shfl(s, k + 2, 64);
      const int s3 = __shfl(s, k + 3, 64);
      const int s4 = __shfl(s, k + 4, 64);
      const int s5 = __shfl(s, k + 5, 64);
      const int s6 = __shfl(s, k + 6, 64);
      const int s7 = __shfl(s, k + 7, 64);
      const float2 h0 = h_row2(H, s0, lane);
      const float2 h1 = h_row2(H, s1, lane);
      const float2 h2 = h_row2(H, s2, lane);
      const float2 h3 = h_row2(H, s3, lane);
      const float2 h4 = h_row2(H, s4, lane);
      const float2 h5 = h_row2(H, s5, lane);
      const float2 h6 = h_row2(H, s6, lane);
      const float2 h7 = h_row2(H, s7, lane);
      const float v0 = __shfl(v, k + 0, 64);
      const float v1 = __shfl(v, k + 1, 64);
      const float v2 = __shfl(v, k + 2, 64);
      const float v3 = __shfl(v, k + 3, 64);
      const float v4 = __shfl(v, k + 4, 64);
      const float v5 = __shfl(v, k + 5, 64);
      const float v6 = __shfl(v, k + 6, 64);
      const float v7 = __shfl(v, k + 7, 64);
      accx = fmaf(v0, h0.x, accx); accy = fmaf(v0, h0.y, accy);
      accx = fmaf(v1, h1.x, accx); accy = fmaf(v1, h1.y, accy);
      accx = fmaf(v2, h2.x, accx); accy = fmaf(v2, h2.y, accy);
      accx = fmaf(v3, h3.x, accx); accy = fmaf(v3, h3.y, accy);
      accx = fmaf(v4, h4.x, accx); accy = fmaf(v4, h4.y, accy);
      accx = fmaf(v5, h5.x, accx); accy = fmaf(v5, h5.y, accy);
      accx = fmaf(v6, h6.x, accx); accy = fmaf(v6, h6.y, accy);
      accx = fmaf(v7, h7.x, accx); accy = fmaf(v7, h7.y, accy);
    }
    for (; k < n; ++k) {
      const int sk = __shfl(s, k, 64);
      const float vk = __shfl(v, k, 64);
      const float2 hv = h_row2(H, sk, lane);
      accx = fmaf(vk, hv.x, accx);
      accy = fmaf(vk, hv.y, accy);
    }
  }
  float2 o;
  o.x = accx;
  o.y = accy;
  reinterpret_cast<float2*>(out + (size_t)wave * OUT_F)[lane] = o;
}

// ---------------------------------------------------------------------------
extern "C" void kernel_launch(void* const* d_in, const int* in_sizes, int n_in,
                              void* d_out, int out_size, void* d_ws,
                              size_t ws_size, hipStream_t stream) {
  const float* X = (const float*)d_in[0];        // [M, 256]
  const float* W = (const float*)d_in[1];        // [256, 128]
  const float* bias = (const float*)d_in[2];     // [128]
  const float* adj_vals = (const float*)d_in[3]; // [E]
  const int* edge_src = (const int*)d_in[4];     // [E]
  const int* edge_dst = (const int*)d_in[5];     // [E]
  float* out = (float*)d_out;                    // [M, 128]

  const int M = in_sizes[0] / IN_F;  // 50000
  const int E = in_sizes[3];         // 800000

  // Workspace layout (16B-aligned slices)
  char* ws = (char*)d_ws;
  size_t o = 0;
  auto take = [&](size_t bytes) {
    void* p = ws + o;
    o = (o + bytes + 15) & ~(size_t)15;
    return p;
  };
  float* H = (float*)take((size_t)M * OUT_F * sizeof(float));  // 25.6 MB
  int* off = (int*)take((size_t)(M + 1) * sizeof(int));
  int* deg = (int*)take((size_t)M * sizeof(int));
  int* cursor = (int*)take((size_t)M * sizeof(int));
  int* perm = (int*)take((size_t)E * sizeof(int));
  (void)ws_size;

  // Zero the two counter arrays (contiguous: deg then cursor)
  hipMemsetAsync(deg, 0, (size_t)2 * M * sizeof(int) + 16, stream);

  dim3 gemm_grid((M + 63) / 64);
  gemm_bias_kernel<<<gemm_grid, 256, 0, stream>>>(X, W, bias, H, M);

  hist_kernel<<<(E + 255) / 256, 256, 0, stream>>>(edge_dst, deg, E);
  scan_kernel<<<1, 1024, 0, stream>>>(deg, off, M);
  scatter_kernel<<<(E + 255) / 256, 256, 0, stream>>>(edge_dst, off, cursor,
                                                      perm, E);

  const int waves_per_block = 4;  // 256 threads
  dim3 gather_grid((M + waves_per_block - 1) / waves_per_block);
  gather_kernel<<<gather_grid, 256, 0, stream>>>(H, adj_vals, edge_src, off,
                                                 perm, out, M);
}

// Round 7
// 225.327 us; speedup vs baseline: 6.2703x; 1.3050x over previous
//
#include <hip/hip_runtime.h>

static constexpr int IN_F = 256;
static constexpr int OUT_F = 128;
static constexpr int BM = 128, BN = 128, BK = 16;

// ---------------------------------------------------------------------------
// Fused: GEMM blocks [0, gemmBlocks) compute H = X*W + bias (128x128 tile,
// 8x8 micro-tile, float4 LDS reads). Blocks >= gemmBlocks run the edge-dst
// histogram (independent inputs) so its latency-bound atomics hide under the
// GEMM's VALU work.
// ---------------------------------------------------------------------------
__global__ __launch_bounds__(256) void gemm_hist_kernel(
    const float* __restrict__ X, const float* __restrict__ W,
    const float* __restrict__ bias, float* __restrict__ H, int M,
    const int* __restrict__ dst, int* __restrict__ deg, int E,
    int gemmBlocks) {
  if ((int)blockIdx.x >= gemmBlocks) {
    int e = ((int)blockIdx.x - gemmBlocks) * 256 + (int)threadIdx.x;
    if (e < E) atomicAdd(&deg[dst[e]], 1);
    return;
  }

  __shared__ float As[BK][BM];  // A transposed: As[k][m]
  __shared__ float Bs[BK][BN];  // Bs[k][n]

  const int tid = threadIdx.x;
  const int tx = tid & 15;   // output col group: cols tx*8 .. tx*8+7
  const int ty = tid >> 4;   // output row group: rows ty*8 .. ty*8+7
  const int row0 = (int)blockIdx.x * BM;

  float acc[8][8];
#pragma unroll
  for (int i = 0; i < 8; ++i)
#pragma unroll
    for (int j = 0; j < 8; ++j) acc[i][j] = 0.f;

  for (int k0 = 0; k0 < IN_F; k0 += BK) {
    // A tile: 128 rows x 16 cols = 512 float4; 2 per thread.
#pragma unroll
    for (int u = 0; u < 2; ++u) {
      const int f = tid + u * 256;
      const int r = f >> 2;
      const int c4 = (f & 3) << 2;
      float4 av = make_float4(0.f, 0.f, 0.f, 0.f);
      const int gr = row0 + r;
      if (gr < M)
        av = *reinterpret_cast<const float4*>(X + (size_t)gr * IN_F + k0 + c4);
      As[c4 + 0][r] = av.x;
      As[c4 + 1][r] = av.y;
      As[c4 + 2][r] = av.z;
      As[c4 + 3][r] = av.w;
    }
    // B tile: 16 rows x 128 cols = 512 float4; 2 per thread.
    {
      const int k = tid >> 5;
      const int n4 = (tid & 31) << 2;
      *reinterpret_cast<float4*>(&Bs[k][n4]) =
          *reinterpret_cast<const float4*>(W + (size_t)(k0 + k) * OUT_F + n4);
      *reinterpret_cast<float4*>(&Bs[k + 8][n4]) =
          *reinterpret_cast<const float4*>(W + (size_t)(k0 + k + 8) * OUT_F + n4);
    }
    __syncthreads();

#pragma unroll
    for (int kk = 0; kk < BK; ++kk) {
      float a[8], b[8];
      *reinterpret_cast<float4*>(&a[0]) =
          *reinterpret_cast<const float4*>(&As[kk][ty * 8]);
      *reinterpret_cast<float4*>(&a[4]) =
          *reinterpret_cast<const float4*>(&As[kk][ty * 8 + 4]);
      *reinterpret_cast<float4*>(&b[0]) =
          *reinterpret_cast<const float4*>(&Bs[kk][tx * 8]);
      *reinterpret_cast<float4*>(&b[4]) =
          *reinterpret_cast<const float4*>(&Bs[kk][tx * 8 + 4]);
#pragma unroll
      for (int i = 0; i < 8; ++i)
#pragma unroll
        for (int j = 0; j < 8; ++j) acc[i][j] = fmaf(a[i], b[j], acc[i][j]);
    }
    __syncthreads();
  }

  float bv[8];
#pragma unroll
  for (int j = 0; j < 8; ++j) bv[j] = bias[tx * 8 + j];

#pragma unroll
  for (int i = 0; i < 8; ++i) {
    const int gr = row0 + ty * 8 + i;
    if (gr < M) {
      float4 o0, o1;
      o0.x = acc[i][0] + bv[0]; o0.y = acc[i][1] + bv[1];
      o0.z = acc[i][2] + bv[2]; o0.w = acc[i][3] + bv[3];
      o1.x = acc[i][4] + bv[4]; o1.y = acc[i][5] + bv[5];
      o1.z = acc[i][6] + bv[6]; o1.w = acc[i][7] + bv[7];
      float4* dstp = reinterpret_cast<float4*>(H + (size_t)gr * OUT_F + tx * 8);
      dstp[0] = o0;
      dstp[1] = o1;
    }
  }
}

// ---------------------------------------------------------------------------
// Hierarchical exclusive scan of deg[n] -> off[n+1], cursor init = off.
// A: per-block (256-elem) partial sums.  B: 1-block scan of partials.
// C: per-block exclusive scan + base; writes off and cursor.
// ---------------------------------------------------------------------------
__global__ __launch_bounds__(256) void scan_partial_kernel(
    const int* __restrict__ deg, int* __restrict__ bsum, int n) {
  __shared__ int red[256];
  const int i = (int)blockIdx.x * 256 + (int)threadIdx.x;
  red[threadIdx.x] = (i < n) ? deg[i] : 0;
  __syncthreads();
  for (int s = 128; s > 0; s >>= 1) {
    if ((int)threadIdx.x < s) red[threadIdx.x] += red[threadIdx.x + s];
    __syncthreads();
  }
  if (threadIdx.x == 0) bsum[blockIdx.x] = red[0];
}

__global__ __launch_bounds__(256) void scan_base_kernel(
    const int* __restrict__ bsum, int* __restrict__ bbase, int nb) {
  __shared__ int sh[256];
  const int t = threadIdx.x;
  const int x = (t < nb) ? bsum[t] : 0;
  sh[t] = x;
  __syncthreads();
  for (int d = 1; d < 256; d <<= 1) {
    const int v = (t >= d) ? sh[t - d] : 0;
    __syncthreads();
    sh[t] += v;
    __syncthreads();
  }
  if (t < nb) bbase[t] = sh[t] - x;  // exclusive
}

__global__ __launch_bounds__(256) void scan_write_kernel(
    const int* __restrict__ deg, const int* __restrict__ bbase,
    int* __restrict__ off, int* __restrict__ cursor, int n) {
  const int i = (int)blockIdx.x * 256 + (int)threadIdx.x;
  const int lane = threadIdx.x & 63;
  const int w = threadIdx.x >> 6;
  const int x = (i < n) ? deg[i] : 0;
  int inc = x;
#pragma unroll
  for (int d = 1; d < 64; d <<= 1) {
    const int t = __shfl_up(inc, d, 64);
    if (lane >= d) inc += t;
  }
  __shared__ int wsum[4];
  if (lane == 63) wsum[w] = inc;
  __syncthreads();
  int wb = 0;
#pragma unroll
  for (int k = 0; k < 4; ++k) wb += (k < w) ? wsum[k] : 0;
  const int excl = bbase[blockIdx.x] + wb + inc - x;
  if (i < n) {
    off[i] = excl;
    cursor[i] = excl;
    if (i == n - 1) off[n] = excl + x;
  }
}

// ---------------------------------------------------------------------------
// Scatter: cursor pre-initialized to off, so the atomic returns the absolute
// slot — no off[d] read on the critical path.
// ---------------------------------------------------------------------------
__global__ __launch_bounds__(256) void scatter_kernel(
    const int* __restrict__ dst, int* __restrict__ cursor,
    int* __restrict__ perm, int E) {
  const int e = (int)blockIdx.x * 256 + (int)threadIdx.x;
  if (e < E) {
    const int pos = atomicAdd(&cursor[dst[e]], 1);
    perm[pos] = e;
  }
}

// ---------------------------------------------------------------------------
// Gather v2 (unchanged): one 64-lane wave per node; lane-parallel metadata,
// shfl broadcast, 8 independent H-row loads in flight. No fp32 atomics.
// ---------------------------------------------------------------------------
__device__ __forceinline__ float2 h_row2(const float* __restrict__ H, int s,
                                         int lane) {
  return reinterpret_cast<const float2*>(H + (size_t)s * OUT_F)[lane];
}

__global__ __launch_bounds__(256) void gather_kernel(
    const float* __restrict__ H, const float* __restrict__ vals,
    const int* __restrict__ src, const int* __restrict__ off,
    const int* __restrict__ perm, float* __restrict__ out, int M) {
  const int wave = (int)((blockIdx.x * blockDim.x + threadIdx.x) >> 6);
  const int lane = threadIdx.x & 63;
  if (wave >= M) return;
  const int b = off[wave];
  const int e = off[wave + 1];
  float accx = 0.f, accy = 0.f;

  for (int base = b; base < e; base += 64) {
    const int n = min(64, e - base);
    int s = 0;
    float v = 0.f;
    if (lane < n) {
      const int id = perm[base + lane];
      v = vals[id];
      s = src[id];
    }
    int k = 0;
    for (; k + 8 <= n; k += 8) {
      const int s0 = __shfl(s, k + 0, 64);
      const int s1 = __shfl(s, k + 1, 64);
      const int s2 = __shfl(s, k + 2, 64);
      const int s3 = __shfl(s, k + 3, 64);
      const int s4 = __shfl(s, k + 4, 64);
      const int s5 = __shfl(s, k + 5, 64);
      const int s6 = __shfl(s, k + 6, 64);
      const int s7 = __shfl(s, k + 7, 64);
      const float2 h0 = h_row2(H, s0, lane);
      const float2 h1 = h_row2(H, s1, lane);
      const float2 h2 = h_row2(H, s2, lane);
      const float2 h3 = h_row2(H, s3, lane);
      const float2 h4 = h_row2(H, s4, lane);
      const float2 h5 = h_row2(H, s5, lane);
      const float2 h6 = h_row2(H, s6, lane);
      const float2 h7 = h_row2(H, s7, lane);
      const float v0 = __shfl(v, k + 0, 64);
      const float v1 = __shfl(v, k + 1, 64);
      const float v2 = __shfl(v, k + 2, 64);
      const float v3 = __shfl(v, k + 3, 64);
      const float v4 = __shfl(v, k + 4, 64);
      const float v5 = __shfl(v, k + 5, 64);
      const float v6 = __shfl(v, k + 6, 64);
      const float v7 = __shfl(v, k + 7, 64);
      accx = fmaf(v0, h0.x, accx); accy = fmaf(v0, h0.y, accy);
      accx = fmaf(v1, h1.x, accx); accy = fmaf(v1, h1.y, accy);
      accx = fmaf(v2, h2.x, accx); accy = fmaf(v2, h2.y, accy);
      accx = fmaf(v3, h3.x, accx); accy = fmaf(v3, h3.y, accy);
      accx = fmaf(v4, h4.x, accx); accy = fmaf(v4, h4.y, accy);
      accx = fmaf(v5, h5.x, accx); accy = fmaf(v5, h5.y, accy);
      accx = fmaf(v6, h6.x, accx); accy = fmaf(v6, h6.y, accy);
      accx = fmaf(v7, h7.x, accx); accy = fmaf(v7, h7.y, accy);
    }
    for (; k < n; ++k) {
      const int sk = __shfl(s, k, 64);
      const float vk = __shfl(v, k, 64);
      const float2 hv = h_row2(H, sk, lane);
      accx = fmaf(vk, hv.x, accx);
      accy = fmaf(vk, hv.y, accy);
    }
  }
  float2 o;
  o.x = accx;
  o.y = accy;
  reinterpret_cast<float2*>(out + (size_t)wave * OUT_F)[lane] = o;
}

// ---------------------------------------------------------------------------
extern "C" void kernel_launch(void* const* d_in, const int* in_sizes, int n_in,
                              void* d_out, int out_size, void* d_ws,
                              size_t ws_size, hipStream_t stream) {
  const float* X = (const float*)d_in[0];        // [M, 256]
  const float* W = (const float*)d_in[1];        // [256, 128]
  const float* bias = (const float*)d_in[2];     // [128]
  const float* adj_vals = (const float*)d_in[3]; // [E]
  const int* edge_src = (const int*)d_in[4];     // [E]
  const int* edge_dst = (const int*)d_in[5];     // [E]
  float* out = (float*)d_out;                    // [M, 128]

  const int M = in_sizes[0] / IN_F;  // 50000
  const int E = in_sizes[3];         // 800000

  // Workspace layout (16B-aligned slices); total ~29.5 MB.
  char* ws = (char*)d_ws;
  size_t o = 0;
  auto take = [&](size_t bytes) {
    void* p = ws + o;
    o = (o + bytes + 15) & ~(size_t)15;
    return p;
  };
  float* H = (float*)take((size_t)M * OUT_F * sizeof(float));  // 25.6 MB
  int* off = (int*)take((size_t)(M + 1) * sizeof(int));
  int* deg = (int*)take((size_t)M * sizeof(int));
  int* cursor = (int*)take((size_t)M * sizeof(int));
  int* perm = (int*)take((size_t)E * sizeof(int));
  const int nb = (M + 255) / 256;  // 196 scan blocks (<= 256)
  int* bsum = (int*)take((size_t)nb * sizeof(int));
  int* bbase = (int*)take((size_t)nb * sizeof(int));
  (void)ws_size;

  hipMemsetAsync(deg, 0, (size_t)M * sizeof(int), stream);

  const int gemmBlocks = (M + BM - 1) / BM;       // 391
  const int histBlocks = (E + 255) / 256;         // 3125
  gemm_hist_kernel<<<gemmBlocks + histBlocks, 256, 0, stream>>>(
      X, W, bias, H, M, edge_dst, deg, E, gemmBlocks);

  scan_partial_kernel<<<nb, 256, 0, stream>>>(deg, bsum, M);
  scan_base_kernel<<<1, 256, 0, stream>>>(bsum, bbase, nb);
  scan_write_kernel<<<nb, 256, 0, stream>>>(deg, bbase, off, cursor, M);

  scatter_kernel<<<(E + 255) / 256, 256, 0, stream>>>(edge_dst, cursor, perm, E);

  const int waves_per_block = 4;  // 256 threads
  dim3 gather_grid((M + waves_per_block - 1) / waves_per_block);
  gather_kernel<<<gather_grid, 256, 0, stream>>>(H, adj_vals, edge_src, off,
                                                 perm, out, M);
}

// Round 8
// 188.804 us; speedup vs baseline: 7.4832x; 1.1934x over previous
//
#include <hip/hip_runtime.h>

static constexpr int IN_F = 256;
static constexpr int OUT_F = 128;
static constexpr int BM = 64, BN = 128, BK = 32;

// ---------------------------------------------------------------------------
// Fused: GEMM blocks [0, gemmBlocks) compute H = X*W + bias.
// BM=64 -> 782 blocks (~3/CU, balanced), BK=32 (half the barriers), 4x8
// micro-tile. Blocks >= gemmBlocks run the edge-dst histogram.
// ---------------------------------------------------------------------------
__global__ __launch_bounds__(256) void gemm_hist_kernel(
    const float* __restrict__ X, const float* __restrict__ W,
    const float* __restrict__ bias, float* __restrict__ H, int M,
    const int* __restrict__ dst, int* __restrict__ deg, int E,
    int gemmBlocks) {
  if ((int)blockIdx.x >= gemmBlocks) {
    int e = ((int)blockIdx.x - gemmBlocks) * 256 + (int)threadIdx.x;
    if (e < E) atomicAdd(&deg[dst[e]], 1);
    return;
  }

  __shared__ float As[BK][BM];  // 32x64 = 8 KB, transposed: As[k][m]
  __shared__ float Bs[BK][BN];  // 32x128 = 16 KB

  const int tid = threadIdx.x;
  const int tx = tid & 15;   // col group: cols tx*8 .. +7
  const int ty = tid >> 4;   // row group: rows ty*4 .. +3
  const int row0 = (int)blockIdx.x * BM;

  float acc[4][8];
#pragma unroll
  for (int i = 0; i < 4; ++i)
#pragma unroll
    for (int j = 0; j < 8; ++j) acc[i][j] = 0.f;

  for (int k0 = 0; k0 < IN_F; k0 += BK) {
    // A tile: 64 rows x 32 cols = 512 float4; 2 per thread.
#pragma unroll
    for (int u = 0; u < 2; ++u) {
      const int f = tid + u * 256;
      const int r = f >> 3;             // 0..63
      const int c4 = (f & 7) << 2;      // 0,4,..,28
      float4 av = make_float4(0.f, 0.f, 0.f, 0.f);
      const int gr = row0 + r;
      if (gr < M)
        av = *reinterpret_cast<const float4*>(X + (size_t)gr * IN_F + k0 + c4);
      As[c4 + 0][r] = av.x;
      As[c4 + 1][r] = av.y;
      As[c4 + 2][r] = av.z;
      As[c4 + 3][r] = av.w;
    }
    // B tile: 32 rows x 128 cols = 1024 float4; 4 per thread.
#pragma unroll
    for (int u = 0; u < 4; ++u) {
      const int f = tid + u * 256;
      const int k = f >> 5;             // 0..31
      const int n4 = (f & 31) << 2;     // 0..124
      *reinterpret_cast<float4*>(&Bs[k][n4]) =
          *reinterpret_cast<const float4*>(W + (size_t)(k0 + k) * OUT_F + n4);
    }
    __syncthreads();

#pragma unroll
    for (int kk = 0; kk < BK; ++kk) {
      float a[4], b[8];
      *reinterpret_cast<float4*>(&a[0]) =
          *reinterpret_cast<const float4*>(&As[kk][ty * 4]);
      *reinterpret_cast<float4*>(&b[0]) =
          *reinterpret_cast<const float4*>(&Bs[kk][tx * 8]);
      *reinterpret_cast<float4*>(&b[4]) =
          *reinterpret_cast<const float4*>(&Bs[kk][tx * 8 + 4]);
#pragma unroll
      for (int i = 0; i < 4; ++i)
#pragma unroll
        for (int j = 0; j < 8; ++j) acc[i][j] = fmaf(a[i], b[j], acc[i][j]);
    }
    __syncthreads();
  }

  float bv[8];
#pragma unroll
  for (int j = 0; j < 8; ++j) bv[j] = bias[tx * 8 + j];

#pragma unroll
  for (int i = 0; i < 4; ++i) {
    const int gr = row0 + ty * 4 + i;
    if (gr < M) {
      float4 o0, o1;
      o0.x = acc[i][0] + bv[0]; o0.y = acc[i][1] + bv[1];
      o0.z = acc[i][2] + bv[2]; o0.w = acc[i][3] + bv[3];
      o1.x = acc[i][4] + bv[4]; o1.y = acc[i][5] + bv[5];
      o1.z = acc[i][6] + bv[6]; o1.w = acc[i][7] + bv[7];
      float4* dstp = reinterpret_cast<float4*>(H + (size_t)gr * OUT_F + tx * 8);
      dstp[0] = o0;
      dstp[1] = o1;
    }
  }
}

// ---------------------------------------------------------------------------
// Hierarchical exclusive scan of deg[n] -> off[n+1], cursor init = off.
// ---------------------------------------------------------------------------
__global__ __launch_bounds__(256) void scan_partial_kernel(
    const int* __restrict__ deg, int* __restrict__ bsum, int n) {
  __shared__ int red[256];
  const int i = (int)blockIdx.x * 256 + (int)threadIdx.x;
  red[threadIdx.x] = (i < n) ? deg[i] : 0;
  __syncthreads();
  for (int s = 128; s > 0; s >>= 1) {
    if ((int)threadIdx.x < s) red[threadIdx.x] += red[threadIdx.x + s];
    __syncthreads();
  }
  if (threadIdx.x == 0) bsum[blockIdx.x] = red[0];
}

__global__ __launch_bounds__(256) void scan_base_kernel(
    const int* __restrict__ bsum, int* __restrict__ bbase, int nb) {
  __shared__ int sh[256];
  const int t = threadIdx.x;
  const int x = (t < nb) ? bsum[t] : 0;
  sh[t] = x;
  __syncthreads();
  for (int d = 1; d < 256; d <<= 1) {
    const int v = (t >= d) ? sh[t - d] : 0;
    __syncthreads();
    sh[t] += v;
    __syncthreads();
  }
  if (t < nb) bbase[t] = sh[t] - x;  // exclusive
}

__global__ __launch_bounds__(256) void scan_write_kernel(
    const int* __restrict__ deg, const int* __restrict__ bbase,
    int* __restrict__ off, int* __restrict__ cursor, int n) {
  const int i = (int)blockIdx.x * 256 + (int)threadIdx.x;
  const int lane = threadIdx.x & 63;
  const int w = threadIdx.x >> 6;
  const int x = (i < n) ? deg[i] : 0;
  int inc = x;
#pragma unroll
  for (int d = 1; d < 64; d <<= 1) {
    const int t = __shfl_up(inc, d, 64);
    if (lane >= d) inc += t;
  }
  __shared__ int wsum[4];
  if (lane == 63) wsum[w] = inc;
  __syncthreads();
  int wb = 0;
#pragma unroll
  for (int k = 0; k < 4; ++k) wb += (k < w) ? wsum[k] : 0;
  const int excl = bbase[blockIdx.x] + wb + inc - x;
  if (i < n) {
    off[i] = excl;
    cursor[i] = excl;
    if (i == n - 1) off[n] = excl + x;
  }
}

// ---------------------------------------------------------------------------
// Scatter variants. Payload version writes (src, val) directly to the CSR
// slot so gather needs no indirection. Perm version is the ws-size fallback.
// ---------------------------------------------------------------------------
__global__ __launch_bounds__(256) void scatter_pay_kernel(
    const int* __restrict__ dst, const int* __restrict__ src,
    const float* __restrict__ vals, int* __restrict__ cursor,
    int2* __restrict__ pay, int E) {
  const int e = (int)blockIdx.x * 256 + (int)threadIdx.x;
  if (e < E) {
    const int pos = atomicAdd(&cursor[dst[e]], 1);
    pay[pos] = make_int2(src[e], __float_as_int(vals[e]));
  }
}

__global__ __launch_bounds__(256) void scatter_perm_kernel(
    const int* __restrict__ dst, int* __restrict__ cursor,
    int* __restrict__ perm, int E) {
  const int e = (int)blockIdx.x * 256 + (int)threadIdx.x;
  if (e < E) {
    const int pos = atomicAdd(&cursor[dst[e]], 1);
    perm[pos] = e;
  }
}

// ---------------------------------------------------------------------------
// Gather: one 64-lane wave per node; lane-parallel metadata, shfl broadcast,
// 8 independent H-row loads in flight. No fp32 atomics.
// ---------------------------------------------------------------------------
__device__ __forceinline__ float2 h_row2(const float* __restrict__ H, int s,
                                         int lane) {
  return reinterpret_cast<const float2*>(H + (size_t)s * OUT_F)[lane];
}

template <bool PAYLOAD>
__device__ __forceinline__ void gather_body(
    const float* __restrict__ H, const int2* __restrict__ pay,
    const float* __restrict__ vals, const int* __restrict__ src,
    const int* __restrict__ perm, const int* __restrict__ off,
    float* __restrict__ out, int M, int wave, int lane) {
  const int b = off[wave];
  const int e = off[wave + 1];
  float accx = 0.f, accy = 0.f;

  for (int base = b; base < e; base += 64) {
    const int n = min(64, e - base);
    int s = 0;
    float v = 0.f;
    if (lane < n) {
      if (PAYLOAD) {
        const int2 p = pay[base + lane];
        s = p.x;
        v = __int_as_float(p.y);
      } else {
        const int id = perm[base + lane];
        v = vals[id];
        s = src[id];
      }
    }
    int k = 0;
    for (; k + 8 <= n; k += 8) {
      const int s0 = __shfl(s, k + 0, 64);
      const int s1 = __shfl(s, k + 1, 64);
      const int s2 = __shfl(s, k + 2, 64);
      const int s3 = __shfl(s, k + 3, 64);
      const int s4 = __shfl(s, k + 4, 64);
      const int s5 = __shfl(s, k + 5, 64);
      const int s6 = __shfl(s, k + 6, 64);
      const int s7 = __shfl(s, k + 7, 64);
      const float2 h0 = h_row2(H, s0, lane);
      const float2 h1 = h_row2(H, s1, lane);
      const float2 h2 = h_row2(H, s2, lane);
      const float2 h3 = h_row2(H, s3, lane);
      const float2 h4 = h_row2(H, s4, lane);
      const float2 h5 = h_row2(H, s5, lane);
      const float2 h6 = h_row2(H, s6, lane);
      const float2 h7 = h_row2(H, s7, lane);
      const float v0 = __shfl(v, k + 0, 64);
      const float v1 = __shfl(v, k + 1, 64);
      const float v2 = __shfl(v, k + 2, 64);
      const float v3 = __shfl(v, k + 3, 64);
      const float v4 = __shfl(v, k + 4, 64);
      const float v5 = __shfl(v, k + 5, 64);
      const float v6 = __shfl(v, k + 6, 64);
      const float v7 = __shfl(v, k + 7, 64);
      accx = fmaf(v0, h0.x, accx); accy = fmaf(v0, h0.y, accy);
      accx = fmaf(v1, h1.x, accx); accy = fmaf(v1, h1.y, accy);
      accx = fmaf(v2, h2.x, accx); accy = fmaf(v2, h2.y, accy);
      accx = fmaf(v3, h3.x, accx); accy = fmaf(v3, h3.y, accy);
      accx = fmaf(v4, h4.x, accx); accy = fmaf(v4, h4.y, accy);
      accx = fmaf(v5, h5.x, accx); accy = fmaf(v5, h5.y, accy);
      accx = fmaf(v6, h6.x, accx); accy = fmaf(v6, h6.y, accy);
      accx = fmaf(v7, h7.x, accx); accy = fmaf(v7, h7.y, accy);
    }
    for (; k < n; ++k) {
      const int sk = __shfl(s, k, 64);
      const float vk = __shfl(v, k, 64);
      const float2 hv = h_row2(H, sk, lane);
      accx = fmaf(vk, hv.x, accx);
      accy = fmaf(vk, hv.y, accy);
    }
  }
  float2 o;
  o.x = accx;
  o.y = accy;
  reinterpret_cast<float2*>(out + (size_t)wave * OUT_F)[lane] = o;
}

__global__ __launch_bounds__(256) void gather_pay_kernel(
    const float* __restrict__ H, const int2* __restrict__ pay,
    const int* __restrict__ off, float* __restrict__ out, int M) {
  const int wave = (int)((blockIdx.x * blockDim.x + threadIdx.x) >> 6);
  const int lane = threadIdx.x & 63;
  if (wave >= M) return;
  gather_body<true>(H, pay, nullptr, nullptr, nullptr, off, out, M, wave, lane);
}

__global__ __launch_bounds__(256) void gather_perm_kernel(
    const float* __restrict__ H, const float* __restrict__ vals,
    const int* __restrict__ src, const int* __restrict__ off,
    const int* __restrict__ perm, float* __restrict__ out, int M) {
  const int wave = (int)((blockIdx.x * blockDim.x + threadIdx.x) >> 6);
  const int lane = threadIdx.x & 63;
  if (wave >= M) return;
  gather_body<false>(H, nullptr, vals, src, perm, off, out, M, wave, lane);
}

// ---------------------------------------------------------------------------
extern "C" void kernel_launch(void* const* d_in, const int* in_sizes, int n_in,
                              void* d_out, int out_size, void* d_ws,
                              size_t ws_size, hipStream_t stream) {
  const float* X = (const float*)d_in[0];        // [M, 256]
  const float* W = (const float*)d_in[1];        // [256, 128]
  const float* bias = (const float*)d_in[2];     // [128]
  const float* adj_vals = (const float*)d_in[3]; // [E]
  const int* edge_src = (const int*)d_in[4];     // [E]
  const int* edge_dst = (const int*)d_in[5];     // [E]
  float* out = (float*)d_out;                    // [M, 128]

  const int M = in_sizes[0] / IN_F;  // 50000
  const int E = in_sizes[3];         // 800000

  char* ws = (char*)d_ws;
  size_t o = 0;
  auto take = [&](size_t bytes) {
    void* p = ws + o;
    o = (o + bytes + 15) & ~(size_t)15;
    return p;
  };
  float* H = (float*)take((size_t)M * OUT_F * sizeof(float));  // 25.6 MB
  int* off = (int*)take((size_t)(M + 1) * sizeof(int));
  int* deg = (int*)take((size_t)M * sizeof(int));
  int* cursor = (int*)take((size_t)M * sizeof(int));
  const int nb = (M + 255) / 256;  // 196 scan blocks (<= 256)

  // Decide payload (int2 per edge) vs perm (int per edge) by ws budget.
  const size_t fixed = o + 2 * (((size_t)nb * sizeof(int) + 15) & ~(size_t)15);
  const bool use_pay = (ws_size == 0) /* unknown: assume generous */ ||
                       (fixed + (size_t)E * sizeof(int2) <= ws_size);

  int2* pay = nullptr;
  int* perm = nullptr;
  if (use_pay)
    pay = (int2*)take((size_t)E * sizeof(int2));
  else
    perm = (int*)take((size_t)E * sizeof(int));
  int* bsum = (int*)take((size_t)nb * sizeof(int));
  int* bbase = (int*)take((size_t)nb * sizeof(int));

  hipMemsetAsync(deg, 0, (size_t)M * sizeof(int), stream);

  const int gemmBlocks = (M + BM - 1) / BM;       // 782
  const int histBlocks = (E + 255) / 256;         // 3125
  gemm_hist_kernel<<<gemmBlocks + histBlocks, 256, 0, stream>>>(
      X, W, bias, H, M, edge_dst, deg, E, gemmBlocks);

  scan_partial_kernel<<<nb, 256, 0, stream>>>(deg, bsum, M);
  scan_base_kernel<<<1, 256, 0, stream>>>(bsum, bbase, nb);
  scan_write_kernel<<<nb, 256, 0, stream>>>(deg, bbase, off, cursor, M);

  const int eb = (E + 255) / 256;
  dim3 gather_grid((M + 3) / 4);  // 4 waves (256 threads) per block
  if (use_pay) {
    scatter_pay_kernel<<<eb, 256, 0, stream>>>(edge_dst, edge_src, adj_vals,
                                               cursor, pay, E);
    gather_pay_kernel<<<gather_grid, 256, 0, stream>>>(H, pay, off, out, M);
  } else {
    scatter_perm_kernel<<<eb, 256, 0, stream>>>(edge_dst, cursor, perm, E);
    gather_perm_kernel<<<gather_grid, 256, 0, stream>>>(H, adj_vals, edge_src,
                                                        off, perm, out, M);
  }
}

// Round 9
// 138.722 us; speedup vs baseline: 10.1848x; 1.3610x over previous
//
#include <hip/hip_runtime.h>

static constexpr int IN_F = 256;
static constexpr int OUT_F = 128;
static constexpr int BM = 64, BN = 128, BK = 32;
static constexpr int NT = IN_F / BK;  // 8 K-tiles

// ---------------------------------------------------------------------------
// Fused kernel. Blocks [0, gemmBlocks): H = X*W + bias with register-prefetch
// double buffering (global loads for tile t+1 issued before compute of tile t)
// and conflict-free LDS layout:
//   As[BK][BM+4]  (stride 68 words: a-read b128 conflict-free, 16B aligned)
//   Bs[BK][BN]    b-read as two float4 at tx*4 / 64+tx*4  -> 2-way (free)
// Blocks >= gemmBlocks: edge-dst histogram; also records each edge's
// within-node slot into tmp[e] (when tmp != nullptr) so the later placement
// pass needs NO atomics.
// ---------------------------------------------------------------------------
__global__ __launch_bounds__(256) void gemm_hist_kernel(
    const float* __restrict__ X, const float* __restrict__ W,
    const float* __restrict__ bias, float* __restrict__ H, int M,
    const int* __restrict__ dst, int* __restrict__ deg,
    int* __restrict__ tmp, int E, int gemmBlocks) {
  if ((int)blockIdx.x >= gemmBlocks) {
    const int e = ((int)blockIdx.x - gemmBlocks) * 256 + (int)threadIdx.x;
    if (e < E) {
      const int s = atomicAdd(&deg[dst[e]], 1);
      if (tmp) tmp[e] = s;
    }
    return;
  }

  __shared__ float As[BK][BM + 4];  // 32 x 68 words = 8704 B
  __shared__ float Bs[BK][BN];      // 32 x 128 words = 16384 B

  const int tid = threadIdx.x;
  const int tx = tid & 15;   // col group
  const int ty = tid >> 4;   // row group (rows ty*4 .. +3)
  const int row0 = (int)blockIdx.x * BM;

  // Staging maps
  const int ar = tid >> 3;          // 0..31 (and +32 for second half)
  const int ac4 = (tid & 7) << 2;   // k-offset 0,4,...,28
  const int bk_ = tid >> 5;         // 0..7
  const int bn4 = (tid & 31) << 2;  // 0..124

  float acc[4][8];
#pragma unroll
  for (int i = 0; i < 4; ++i)
#pragma unroll
    for (int j = 0; j < 8; ++j) acc[i][j] = 0.f;

  const float4 fz = make_float4(0.f, 0.f, 0.f, 0.f);
  const int gr0 = row0 + ar;
  const int gr1 = row0 + ar + 32;

  // Prologue: load tile 0 into registers.
  float4 cA0 = (gr0 < M) ? *(const float4*)(X + (size_t)gr0 * IN_F + ac4) : fz;
  float4 cA1 = (gr1 < M) ? *(const float4*)(X + (size_t)gr1 * IN_F + ac4) : fz;
  float4 cB0 = *(const float4*)(W + (size_t)(bk_ + 0) * OUT_F + bn4);
  float4 cB1 = *(const float4*)(W + (size_t)(bk_ + 8) * OUT_F + bn4);
  float4 cB2 = *(const float4*)(W + (size_t)(bk_ + 16) * OUT_F + bn4);
  float4 cB3 = *(const float4*)(W + (size_t)(bk_ + 24) * OUT_F + bn4);

#pragma unroll 1
  for (int t = 0; t < NT; ++t) {
    // Stage current tile registers -> LDS.
    As[ac4 + 0][ar] = cA0.x;
    As[ac4 + 1][ar] = cA0.y;
    As[ac4 + 2][ar] = cA0.z;
    As[ac4 + 3][ar] = cA0.w;
    As[ac4 + 0][ar + 32] = cA1.x;
    As[ac4 + 1][ar + 32] = cA1.y;
    As[ac4 + 2][ar + 32] = cA1.z;
    As[ac4 + 3][ar + 32] = cA1.w;
    *(float4*)&Bs[bk_ + 0][bn4] = cB0;
    *(float4*)&Bs[bk_ + 8][bn4] = cB1;
    *(float4*)&Bs[bk_ + 16][bn4] = cB2;
    *(float4*)&Bs[bk_ + 24][bn4] = cB3;
    __syncthreads();

    // Prefetch next tile (stays in flight through the whole compute phase).
    if (t + 1 < NT) {
      const int k0 = (t + 1) * BK;
      cA0 = (gr0 < M) ? *(const float4*)(X + (size_t)gr0 * IN_F + k0 + ac4) : fz;
      cA1 = (gr1 < M) ? *(const float4*)(X + (size_t)gr1 * IN_F + k0 + ac4) : fz;
      cB0 = *(const float4*)(W + (size_t)(k0 + bk_ + 0) * OUT_F + bn4);
      cB1 = *(const float4*)(W + (size_t)(k0 + bk_ + 8) * OUT_F + bn4);
      cB2 = *(const float4*)(W + (size_t)(k0 + bk_ + 16) * OUT_F + bn4);
      cB3 = *(const float4*)(W + (size_t)(k0 + bk_ + 24) * OUT_F + bn4);
    }

#pragma unroll
    for (int kk = 0; kk < BK; ++kk) {
      const float4 a = *(const float4*)&As[kk][ty * 4];
      const float4 b0 = *(const float4*)&Bs[kk][tx * 4];
      const float4 b1 = *(const float4*)&Bs[kk][64 + tx * 4];
      const float av[4] = {a.x, a.y, a.z, a.w};
#pragma unroll
      for (int i = 0; i < 4; ++i) {
        acc[i][0] = fmaf(av[i], b0.x, acc[i][0]);
        acc[i][1] = fmaf(av[i], b0.y, acc[i][1]);
        acc[i][2] = fmaf(av[i], b0.z, acc[i][2]);
        acc[i][3] = fmaf(av[i], b0.w, acc[i][3]);
        acc[i][4] = fmaf(av[i], b1.x, acc[i][4]);
        acc[i][5] = fmaf(av[i], b1.y, acc[i][5]);
        acc[i][6] = fmaf(av[i], b1.z, acc[i][6]);
        acc[i][7] = fmaf(av[i], b1.w, acc[i][7]);
      }
    }
    __syncthreads();
  }

  float bv0[4], bv1[4];
#pragma unroll
  for (int j = 0; j < 4; ++j) {
    bv0[j] = bias[tx * 4 + j];
    bv1[j] = bias[64 + tx * 4 + j];
  }
#pragma unroll
  for (int i = 0; i < 4; ++i) {
    const int gr = row0 + ty * 4 + i;
    if (gr < M) {
      float4 o0, o1;
      o0.x = acc[i][0] + bv0[0]; o0.y = acc[i][1] + bv0[1];
      o0.z = acc[i][2] + bv0[2]; o0.w = acc[i][3] + bv0[3];
      o1.x = acc[i][4] + bv1[0]; o1.y = acc[i][5] + bv1[1];
      o1.z = acc[i][6] + bv1[2]; o1.w = acc[i][7] + bv1[3];
      *(float4*)(H + (size_t)gr * OUT_F + tx * 4) = o0;
      *(float4*)(H + (size_t)gr * OUT_F + 64 + tx * 4) = o1;
    }
  }
}

// ---------------------------------------------------------------------------
// Hierarchical exclusive scan of deg[n] -> off[n+1]; optional cursor=off copy.
// ---------------------------------------------------------------------------
__global__ __launch_bounds__(256) void scan_partial_kernel(
    const int* __restrict__ deg, int* __restrict__ bsum, int n) {
  __shared__ int red[256];
  const int i = (int)blockIdx.x * 256 + (int)threadIdx.x;
  red[threadIdx.x] = (i < n) ? deg[i] : 0;
  __syncthreads();
  for (int s = 128; s > 0; s >>= 1) {
    if ((int)threadIdx.x < s) red[threadIdx.x] += red[threadIdx.x + s];
    __syncthreads();
  }
  if (threadIdx.x == 0) bsum[blockIdx.x] = red[0];
}

__global__ __launch_bounds__(256) void scan_base_kernel(
    const int* __restrict__ bsum, int* __restrict__ bbase, int nb) {
  __shared__ int sh[256];
  const int t = threadIdx.x;
  const int x = (t < nb) ? bsum[t] : 0;
  sh[t] = x;
  __syncthreads();
  for (int d = 1; d < 256; d <<= 1) {
    const int v = (t >= d) ? sh[t - d] : 0;
    __syncthreads();
    sh[t] += v;
    __syncthreads();
  }
  if (t < nb) bbase[t] = sh[t] - x;  // exclusive
}

__global__ __launch_bounds__(256) void scan_write_kernel(
    const int* __restrict__ deg, const int* __restrict__ bbase,
    int* __restrict__ off, int* __restrict__ cursor, int n) {
  const int i = (int)blockIdx.x * 256 + (int)threadIdx.x;
  const int lane = threadIdx.x & 63;
  const int w = threadIdx.x >> 6;
  const int x = (i < n) ? deg[i] : 0;
  int inc = x;
#pragma unroll
  for (int d = 1; d < 64; d <<= 1) {
    const int t = __shfl_up(inc, d, 64);
    if (lane >= d) inc += t;
  }
  __shared__ int wsum[4];
  if (lane == 63) wsum[w] = inc;
  __syncthreads();
  int wb = 0;
#pragma unroll
  for (int k = 0; k < 4; ++k) wb += (k < w) ? wsum[k] : 0;
  const int excl = bbase[blockIdx.x] + wb + inc - x;
  if (i < n) {
    off[i] = excl;
    if (cursor) cursor[i] = excl;
    if (i == n - 1) off[n] = excl + x;
  }
}

// ---------------------------------------------------------------------------
// Placement (primary, NO atomics): pos = off[dst[e]] + tmp[e].
// ---------------------------------------------------------------------------
__global__ __launch_bounds__(256) void place_kernel(
    const int* __restrict__ dst, const int* __restrict__ src,
    const float* __restrict__ vals, const int* __restrict__ off,
    const int* __restrict__ tmp, int2* __restrict__ pay, int E) {
  const int e = (int)blockIdx.x * 256 + (int)threadIdx.x;
  if (e < E) {
    const int pos = off[dst[e]] + tmp[e];
    pay[pos] = make_int2(src[e], __float_as_int(vals[e]));
  }
}

// Fallback scatters (atomic cursor).
__global__ __launch_bounds__(256) void scatter_pay_kernel(
    const int* __restrict__ dst, const int* __restrict__ src,
    const float* __restrict__ vals, int* __restrict__ cursor,
    int2* __restrict__ pay, int E) {
  const int e = (int)blockIdx.x * 256 + (int)threadIdx.x;
  if (e < E) {
    const int pos = atomicAdd(&cursor[dst[e]], 1);
    pay[pos] = make_int2(src[e], __float_as_int(vals[e]));
  }
}

__global__ __launch_bounds__(256) void scatter_perm_kernel(
    const int* __restrict__ dst, int* __restrict__ cursor,
    int* __restrict__ perm, int E) {
  const int e = (int)blockIdx.x * 256 + (int)threadIdx.x;
  if (e < E) {
    const int pos = atomicAdd(&cursor[dst[e]], 1);
    perm[pos] = e;
  }
}

// ---------------------------------------------------------------------------
// Gather: one 64-lane wave per node; lane-parallel metadata, shfl broadcast,
// 8 independent H-row loads in flight. No fp32 atomics.
// ---------------------------------------------------------------------------
__device__ __forceinline__ float2 h_row2(const float* __restrict__ H, int s,
                                         int lane) {
  return reinterpret_cast<const float2*>(H + (size_t)s * OUT_F)[lane];
}

template <bool PAYLOAD>
__device__ __forceinline__ void gather_body(
    const float* __restrict__ H, const int2* __restrict__ pay,
    const float* __restrict__ vals, const int* __restrict__ src,
    const int* __restrict__ perm, const int* __restrict__ off,
    float* __restrict__ out, int wave, int lane) {
  const int b = off[wave];
  const int e = off[wave + 1];
  float accx = 0.f, accy = 0.f;

  for (int base = b; base < e; base += 64) {
    const int n = min(64, e - base);
    int s = 0;
    float v = 0.f;
    if (lane < n) {
      if (PAYLOAD) {
        const int2 p = pay[base + lane];
        s = p.x;
        v = __int_as_float(p.y);
      } else {
        const int id = perm[base + lane];
        v = vals[id];
        s = src[id];
      }
    }
    int k = 0;
    for (; k + 8 <= n; k += 8) {
      const int s0 = __shfl(s, k + 0, 64);
      const int s1 = __shfl(s, k + 1, 64);
      const int s2 = __shfl(s, k + 2, 64);
      const int s3 = __shfl(s, k + 3, 64);
      const int s4 = __shfl(s, k + 4, 64);
      const int s5 = __shfl(s, k + 5, 64);
      const int s6 = __shfl(s, k + 6, 64);
      const int s7 = __shfl(s, k + 7, 64);
      const float2 h0 = h_row2(H, s0, lane);
      const float2 h1 = h_row2(H, s1, lane);
      const float2 h2 = h_row2(H, s2, lane);
      const float2 h3 = h_row2(H, s3, lane);
      const float2 h4 = h_row2(H, s4, lane);
      const float2 h5 = h_row2(H, s5, lane);
      const float2 h6 = h_row2(H, s6, lane);
      const float2 h7 = h_row2(H, s7, lane);
      const float v0 = __shfl(v, k + 0, 64);
      const float v1 = __shfl(v, k + 1, 64);
      const float v2 = __shfl(v, k + 2, 64);
      const float v3 = __shfl(v, k + 3, 64);
      const float v4 = __shfl(v, k + 4, 64);
      const float v5 = __shfl(v, k + 5, 64);
      const float v6 = __shfl(v, k + 6, 64);
      const float v7 = __shfl(v, k + 7, 64);
      accx = fmaf(v0, h0.x, accx); accy = fmaf(v0, h0.y, accy);
      accx = fmaf(v1, h1.x, accx); accy = fmaf(v1, h1.y, accy);
      accx = fmaf(v2, h2.x, accx); accy = fmaf(v2, h2.y, accy);
      accx = fmaf(v3, h3.x, accx); accy = fmaf(v3, h3.y, accy);
      accx = fmaf(v4, h4.x, accx); accy = fmaf(v4, h4.y, accy);
      accx = fmaf(v5, h5.x, accx); accy = fmaf(v5, h5.y, accy);
      accx = fmaf(v6, h6.x, accx); accy = fmaf(v6, h6.y, accy);
      accx = fmaf(v7, h7.x, accx); accy = fmaf(v7, h7.y, accy);
    }
    for (; k < n; ++k) {
      const int sk = __shfl(s, k, 64);
      const float vk = __shfl(v, k, 64);
      const float2 hv = h_row2(H, sk, lane);
      accx = fmaf(vk, hv.x, accx);
      accy = fmaf(vk, hv.y, accy);
    }
  }
  float2 o;
  o.x = accx;
  o.y = accy;
  reinterpret_cast<float2*>(out + (size_t)wave * OUT_F)[lane] = o;
}

__global__ __launch_bounds__(256) void gather_pay_kernel(
    const float* __restrict__ H, const int2* __restrict__ pay,
    const int* __restrict__ off, float* __restrict__ out, int M) {
  const int wave = (int)((blockIdx.x * blockDim.x + threadIdx.x) >> 6);
  const int lane = threadIdx.x & 63;
  if (wave >= M) return;
  gather_body<true>(H, pay, nullptr, nullptr, nullptr, off, out, wave, lane);
}

__global__ __launch_bounds__(256) void gather_perm_kernel(
    const float* __restrict__ H, const float* __restrict__ vals,
    const int* __restrict__ src, const int* __restrict__ off,
    const int* __restrict__ perm, float* __restrict__ out, int M) {
  const int wave = (int)((blockIdx.x * blockDim.x + threadIdx.x) >> 6);
  const int lane = threadIdx.x & 63;
  if (wave >= M) return;
  gather_body<false>(H, nullptr, vals, src, perm, off, out, wave, lane);
}

// ---------------------------------------------------------------------------
extern "C" void kernel_launch(void* const* d_in, const int* in_sizes, int n_in,
                              void* d_out, int out_size, void* d_ws,
                              size_t ws_size, hipStream_t stream) {
  const float* X = (const float*)d_in[0];        // [M, 256]
  const float* W = (const float*)d_in[1];        // [256, 128]
  const float* bias = (const float*)d_in[2];     // [128]
  const float* adj_vals = (const float*)d_in[3]; // [E]
  const int* edge_src = (const int*)d_in[4];     // [E]
  const int* edge_dst = (const int*)d_in[5];     // [E]
  float* out = (float*)d_out;                    // [M, 128]

  const int M = in_sizes[0] / IN_F;  // 50000
  const int E = in_sizes[3];         // 800000

  char* ws = (char*)d_ws;
  size_t o = 0;
  auto take = [&](size_t bytes) {
    void* p = ws + o;
    o = (o + bytes + 15) & ~(size_t)15;
    return p;
  };
  float* H = (float*)take((size_t)M * OUT_F * sizeof(float));  // 25.6 MB
  int* off = (int*)take((size_t)(M + 1) * sizeof(int));
  int* deg = (int*)take((size_t)M * sizeof(int));
  const int nb = (M + 255) / 256;  // 196 (<= 256)
  const size_t scanb = 2 * (((size_t)nb * sizeof(int) + 15) & ~(size_t)15);

  // Tier select by ws budget (deterministic; visible via which kernels run).
  const size_t base = o;
  const size_t need_primary = base + ((size_t)E + M) * sizeof(int) +
                              (size_t)E * sizeof(int2) + scanb + 64;
  const size_t need_fb1 =
      base + (size_t)M * sizeof(int) + (size_t)E * sizeof(int2) + scanb + 64;
  const int tier = (ws_size == 0 || need_primary <= ws_size) ? 0
                   : (need_fb1 <= ws_size)                   ? 1
                                                             : 2;

  int *tmp = nullptr, *cursor = nullptr, *perm = nullptr;
  int2* pay = nullptr;
  if (tier == 0) {
    tmp = (int*)take((size_t)E * sizeof(int));
    pay = (int2*)take((size_t)E * sizeof(int2));
  } else if (tier == 1) {
    cursor = (int*)take((size_t)M * sizeof(int));
    pay = (int2*)take((size_t)E * sizeof(int2));
  } else {
    cursor = (int*)take((size_t)M * sizeof(int));
    perm = (int*)take((size_t)E * sizeof(int));
  }
  int* bsum = (int*)take((size_t)nb * sizeof(int));
  int* bbase = (int*)take((size_t)nb * sizeof(int));

  hipMemsetAsync(deg, 0, (size_t)M * sizeof(int), stream);

  const int gemmBlocks = (M + BM - 1) / BM;  // 782
  const int histBlocks = (E + 255) / 256;    // 3125
  gemm_hist_kernel<<<gemmBlocks + histBlocks, 256, 0, stream>>>(
      X, W, bias, H, M, edge_dst, deg, tmp, E, gemmBlocks);

  scan_partial_kernel<<<nb, 256, 0, stream>>>(deg, bsum, M);
  scan_base_kernel<<<1, 256, 0, stream>>>(bsum, bbase, nb);
  scan_write_kernel<<<nb, 256, 0, stream>>>(deg, bbase, off, cursor, M);

  const int eb = (E + 255) / 256;
  dim3 gather_grid((M + 3) / 4);  // 4 waves (256 threads) per block
  if (tier == 0) {
    place_kernel<<<eb, 256, 0, stream>>>(edge_dst, edge_src, adj_vals, off,
                                         tmp, pay, E);
    gather_pay_kernel<<<gather_grid, 256, 0, stream>>>(H, pay, off, out, M);
  } else if (tier == 1) {
    scatter_pay_kernel<<<eb, 256, 0, stream>>>(edge_dst, edge_src, adj_vals,
                                               cursor, pay, E);
    gather_pay_kernel<<<gather_grid, 256, 0, stream>>>(H, pay, off, out, M);
  } else {
    scatter_perm_kernel<<<eb, 256, 0, stream>>>(edge_dst, cursor, perm, E);
    gather_perm_kernel<<<gather_grid, 256, 0, stream>>>(H, adj_vals, edge_src,
                                                        off, perm, out, M);
  }
}